// Round 18
// baseline (1060.905 us; speedup 1.0000x reference)
//
#include <hip/hip_runtime.h>
#include <math.h>

#define N_NODES 100000
#define N_EDGES 1600000
#define TOT (2 * N_NODES)            // CSR buckets: 2*row + adj
#define SCAN_NB 256
#define SCAN_CH 4                    // 256*256*4 = 262144 >= 2N+1

static inline int cdiv(long a, long b) { return (int)((a + b - 1) / b); }

typedef unsigned int uint;
typedef unsigned short ushort;
typedef __attribute__((ext_vector_type(8))) short short8v;   // 8 bf16 (4 VGPR)
typedef __attribute__((ext_vector_type(4))) float f32x4;

__device__ inline float bf2f(uint u) { return __uint_as_float(u << 16); }
__device__ inline ushort f2bf(float f) {
    uint u = __float_as_uint(f);
    uint r = ((u >> 16) & 1u) + 0x7fffu;   // RNE
    return (ushort)((u + r) >> 16);
}

// ---------------- MFMA bf16 GEMM: C[i,m] = sum_k A[i,k]*B[k,m] --------------
// ATTN (M==128 only): fused attention feature dots from fp32 accumulators.
template <int K, int M, bool AF32, int OUT, bool ELU, bool LOSS, bool ATTN>
__global__ __launch_bounds__(256) void gemm_mfma(const void* __restrict__ Av,
                                                 const ushort* __restrict__ Bcm,
                                                 void* __restrict__ Cv,
                                                 void* __restrict__ Cv2,
                                                 const float* __restrict__ Xref,
                                                 float* __restrict__ partial,
                                                 const float* __restrict__ va,
                                                 const float* __restrict__ vb,
                                                 const float* __restrict__ pva,
                                                 const float* __restrict__ pvb,
                                                 float* __restrict__ f1,
                                                 float* __restrict__ f2,
                                                 float* __restrict__ pf1,
                                                 float* __restrict__ pf2,
                                                 int nrows) {
    constexpr int BM = 128;
    constexpr int KP = K + 8;
    constexpr int NCT = M / 16;
    __shared__ ushort Blds[M * KP];
    __shared__ ushort Alds[BM * 32];
    const int w = threadIdx.x >> 6;
    const int l = threadIdx.x & 63;
    const int rowg = l & 15;
    const int kg = l >> 4;
    const int rbase = blockIdx.x * BM;
    {
        const uint4* src = reinterpret_cast<const uint4*>(Bcm);
        uint4* dst = reinterpret_cast<uint4*>(Blds);
        const int total = M * KP / 8;
        for (int i = threadIdx.x; i < total; i += 256) dst[i] = src[i];
    }
    f32x4 acc[2][NCT] = {};
    for (int k0 = 0; k0 < K; k0 += 32) {
        __syncthreads();
        int r = threadIdx.x >> 1;
        int kk = (threadIdx.x & 1) * 16;
        int rg = min(rbase + r, nrows - 1);
        if (AF32) {
            const float* A = (const float*)Av;
            const float4* src = reinterpret_cast<const float4*>(A + (size_t)rg * K + k0 + kk);
            ushort* dst = &Alds[r * 32 + kk];
#pragma unroll
            for (int q = 0; q < 4; ++q) {
                float4 v = src[q];
                dst[4 * q + 0] = f2bf(v.x); dst[4 * q + 1] = f2bf(v.y);
                dst[4 * q + 2] = f2bf(v.z); dst[4 * q + 3] = f2bf(v.w);
            }
        } else {
            const ushort* A = (const ushort*)Av;
            const uint4* src = reinterpret_cast<const uint4*>(A + (size_t)rg * K + k0 + kk);
            uint4* dst = reinterpret_cast<uint4*>(&Alds[r * 32 + kk]);
            dst[0] = src[0];
            dst[1] = src[1];
        }
        __syncthreads();
#pragma unroll
        for (int rt = 0; rt < 2; ++rt) {
            short8v af = *reinterpret_cast<const short8v*>(
                &Alds[(w * 32 + rt * 16 + rowg) * 32 + kg * 8]);
#pragma unroll
            for (int ct = 0; ct < NCT; ++ct) {
                short8v bf = *reinterpret_cast<const short8v*>(
                    &Blds[(ct * 16 + rowg) * KP + k0 + kg * 8]);
                acc[rt][ct] = __builtin_amdgcn_mfma_f32_16x16x32_bf16(
                    af, bf, acc[rt][ct], 0, 0, 0);
            }
        }
    }
    float lsum = 0.f;
#pragma unroll
    for (int rt = 0; rt < 2; ++rt) {
#pragma unroll
        for (int q = 0; q < 4; ++q) {
            int r = rbase + w * 32 + rt * 16 + kg * 4 + q;
            if (r >= nrows) continue;
#pragma unroll
            for (int ct = 0; ct < NCT; ++ct) {
                float o = acc[rt][ct][q];
                if (ELU) o = o > 0.f ? o : expm1f(o);
                int col = ct * 16 + rowg;
                if (OUT == 0 || OUT == 3) ((float*)Cv)[(size_t)r * M + col] = o;
                if (OUT == 2) ((ushort*)Cv)[(size_t)r * M + col] = f2bf(o);
                if (OUT == 3) ((ushort*)Cv2)[(size_t)r * M + col] = f2bf(o);
                if (LOSS) {
                    float d = o - Xref[(size_t)r * 256 + col];
                    lsum += d * d;
                }
            }
        }
    }
    if (ATTN) {
        float var[NCT], vbr[NCT], pvar[NCT], pvbr[NCT];
#pragma unroll
        for (int ct = 0; ct < NCT; ++ct) {
            int col = ct * 16 + rowg;
            var[ct] = va[col]; vbr[ct] = vb[col];
            pvar[ct] = pva[col]; pvbr[ct] = pvb[col];
        }
#pragma unroll
        for (int rt = 0; rt < 2; ++rt) {
#pragma unroll
            for (int q = 0; q < 4; ++q) {
                int r = rbase + w * 32 + rt * 16 + kg * 4 + q;
                float da = 0.f, db = 0.f, dpa = 0.f, dpb = 0.f;
#pragma unroll
                for (int ct = 0; ct < NCT; ++ct) {
                    float o = acc[rt][ct][q];
                    da += o * var[ct]; db += o * vbr[ct];
                    dpa += o * pvar[ct]; dpb += o * pvbr[ct];
                }
#pragma unroll
                for (int m = 1; m < 16; m <<= 1) {
                    da += __shfl_xor(da, m); db += __shfl_xor(db, m);
                    dpa += __shfl_xor(dpa, m); dpb += __shfl_xor(dpb, m);
                }
                if (rowg == 0 && r < nrows) {
                    f1[r] = da; f2[r] = db; pf1[r] = dpa; pf2[r] = dpb;
                }
            }
        }
    }
    if (LOSS) {
        __shared__ float smRed[4];
#pragma unroll
        for (int off = 32; off > 0; off >>= 1) lsum += __shfl_down(lsum, off);
        __syncthreads();
        if (l == 0) smRed[w] = lsum;
        __syncthreads();
        if (threadIdx.x == 0)
            partial[blockIdx.x] = smRed[0] + smRed[1] + smRed[2] + smRed[3];
    }
}

// ---------------- weight prep: B1 + B8 only (B5/B7 GEMMs now fused) ---------
__global__ __launch_bounds__(256) void prep_all_kernel(const float* __restrict__ W0,
                                                       ushort* __restrict__ B1,
                                                       ushort* __restrict__ B8) {
    int i = blockIdx.x * 256 + threadIdx.x;
    if (i < 32768) {                            // B1[m][k] = W0[k][m], K=256 M=128
        int k = i / 128, m = i - k * 128;
        B1[m * 264 + k] = f2bf(W0[i]);
    } else if (i < 65536) {                     // B8[m][k] = W0[m][k], K=128 M=256
        int j = i - 32768;
        int m = j / 128, k = j - m * 128;
        B8[m * 136 + k] = f2bf(W0[j]);
    }
}

// ---------------- CSR build: bucket = 2*row + adj, rows padded to x8 --------
__global__ __launch_bounds__(256) void hist2_kernel(const int* __restrict__ rows,
                                                    const int* __restrict__ prows,
                                                    int* __restrict__ deg) {
    int e = blockIdx.x * 256 + threadIdx.x;
    if (e >= 2 * N_EDGES) return;
    int b = e < N_EDGES ? rows[e] * 2 : prows[e - N_EDGES] * 2 + 1;
    atomicAdd(&deg[b], 1);
}

__device__ inline int pad8(int d) { return (d + 7) & ~7; }

__global__ __launch_bounds__(256) void scan1_kernel(const int* __restrict__ deg,
                                                    int* __restrict__ bsum) {
    __shared__ int sm[256];
    int base = (blockIdx.x * 256 + threadIdx.x) * SCAN_CH;
    int s = 0;
#pragma unroll
    for (int i = 0; i < SCAN_CH; ++i) {
        int idx = base + i;
        if (idx < TOT) s += pad8(deg[idx]);
    }
    sm[threadIdx.x] = s;
    __syncthreads();
    for (int off = 128; off > 0; off >>= 1) {
        if (threadIdx.x < off) sm[threadIdx.x] += sm[threadIdx.x + off];
        __syncthreads();
    }
    if (threadIdx.x == 0) bsum[blockIdx.x] = sm[0];
}

__global__ __launch_bounds__(256) void scan3_kernel(const int* __restrict__ deg,
                                                    const int* __restrict__ bsum,
                                                    int* __restrict__ rp) {
    __shared__ int sm[256];
    __shared__ int base0;
    if (threadIdx.x == 0) {
        int run = 0;
        for (int i = 0; i < blockIdx.x; ++i) run += bsum[i];
        base0 = run;
    }
    int base = (blockIdx.x * 256 + threadIdx.x) * SCAN_CH;
    int s = 0;
#pragma unroll
    for (int i = 0; i < SCAN_CH; ++i) {
        int idx = base + i;
        if (idx < TOT) s += pad8(deg[idx]);
    }
    sm[threadIdx.x] = s;
    __syncthreads();
    if (threadIdx.x == 0) {
        int run = base0;
        for (int t = 0; t < 256; ++t) { int tmp = sm[t]; sm[t] = run; run += tmp; }
    }
    __syncthreads();
    int off = sm[threadIdx.x];
#pragma unroll
    for (int i = 0; i < SCAN_CH; ++i) {
        int idx = base + i;
        if (idx < TOT) { rp[idx] = off; off += pad8(deg[idx]); }
        else if (idx == TOT) rp[idx] = off;
    }
}

__global__ __launch_bounds__(256) void scatter_kernel(const int* __restrict__ rlist,
                                                      const int* __restrict__ clist,
                                                      int adj,
                                                      const int* __restrict__ rp,
                                                      int* __restrict__ cur,
                                                      int* __restrict__ ccol) {
    int e = blockIdx.x * 256 + threadIdx.x;
    if (e >= N_EDGES) return;
    int b = rlist[e] * 2 + adj;
    int pos = rp[b] + atomicAdd(&cur[b], 1);
    ccol[pos] = clist[e];
}

// ---------------- edge weights: pre-normalized+scaled; pad slots = {0,0} ----
__global__ __launch_bounds__(256) void edgeval_kernel(const int* __restrict__ rp,
                                                      const int* __restrict__ deg,
                                                      const int* __restrict__ ccol,
                                                      const float* __restrict__ f1,
                                                      const float* __restrict__ f2,
                                                      const float* __restrict__ pf1,
                                                      const float* __restrict__ pf2,
                                                      int2* __restrict__ eg) {
    int b = blockIdx.x * 16 + (threadIdx.x >> 4);
    int sl = threadIdx.x & 15;
    int adj = b & 1, r = b >> 1;
    float f1r = adj ? pf1[r] : f1[r];
    const float* f2t = adj ? pf2 : f2;
    float scale = adj ? 0.8f : 0.2f;
    int j0 = rp[b];
    int realend = j0 + deg[b];
    int pend = rp[b + 1];
    float s = 0.f;
    for (int j = j0 + sl; j < realend; j += 16)
        s += __expf(f1r + f2t[ccol[j]]);
#pragma unroll
    for (int off = 8; off > 0; off >>= 1) s += __shfl_xor(s, off);
    float inv = s > 0.f ? scale / s : 0.f;
    for (int j = j0 + sl; j < pend; j += 16) {
        if (j < realend) {
            int c = ccol[j];
            float wv = __expf(f1r + f2t[c]) * inv;
            eg[j] = make_int2(c, __float_as_int(wv));
        } else {
            eg[j] = make_int2(0, 0);
        }
    }
}

// ---------------- encoder spmm + fused @W1 matvec ---------------------------
// gathers 128-wide bf16 H1; wave r-row in regs -> LDS -> Henc[r][lane] (fp32+bf16)
#define SPU 8
__global__ __launch_bounds__(256) void spmm_enc_kernel(const int* __restrict__ rp,
                                                       const int2* __restrict__ eg,
                                                       const ushort* __restrict__ Hb,
                                                       const float* __restrict__ W1,
                                                       float* __restrict__ Henc,
                                                       ushort* __restrict__ HencB) {
    __shared__ ushort W1lds[128 * 72];          // W1[k][m] bf16, padded 72
    __shared__ float sRow[4][128];
    for (int i = threadIdx.x; i < 8192; i += 256) {
        int k = i >> 6, m = i & 63;
        W1lds[k * 72 + m] = f2bf(W1[i]);
    }
    __syncthreads();
    int r = blockIdx.x * 4 + (threadIdx.x >> 6);
    int wid = threadIdx.x >> 6;
    int lane = threadIdx.x & 63;
    const uint* Hu = reinterpret_cast<const uint*>(Hb);
    float a0 = 0.f, a1 = 0.f;
    int j = rp[2 * r], E = rp[2 * r + 2];       // wave-uniform bounds
    if (j < E) {
        int2 d[SPU]; uint h[SPU];
#pragma unroll
        for (int u = 0; u < SPU; ++u) d[u] = eg[j + u];
#pragma unroll
        for (int u = 0; u < SPU; ++u) h[u] = Hu[(uint)d[u].x * 64u + lane];
        j += SPU;
        for (; j < E; j += SPU) {
            int2 dn[SPU]; uint hn[SPU];
#pragma unroll
            for (int u = 0; u < SPU; ++u) dn[u] = eg[j + u];
#pragma unroll
            for (int u = 0; u < SPU; ++u) hn[u] = Hu[(uint)dn[u].x * 64u + lane];
#pragma unroll
            for (int u = 0; u < SPU; ++u) {
                float v = __int_as_float(d[u].y);
                a0 += v * bf2f(h[u] & 0xffffu);
                a1 += v * bf2f(h[u] >> 16);
            }
#pragma unroll
            for (int u = 0; u < SPU; ++u) { d[u] = dn[u]; h[u] = hn[u]; }
        }
#pragma unroll
        for (int u = 0; u < SPU; ++u) {
            float v = __int_as_float(d[u].y);
            a0 += v * bf2f(h[u] & 0xffffu);
            a1 += v * bf2f(h[u] >> 16);
        }
    }
    a0 = a0 > 0.f ? a0 : expm1f(a0);
    a1 = a1 > 0.f ? a1 : expm1f(a1);
    sRow[wid][2 * lane] = a0;
    sRow[wid][2 * lane + 1] = a1;
    asm volatile("s_waitcnt lgkmcnt(0)" ::: "memory");
    __builtin_amdgcn_sched_barrier(0);
    // Henc[r][lane] = sum_k row[k] * W1[k][lane]
    float acc = 0.f;
#pragma unroll 8
    for (int k = 0; k < 128; ++k)
        acc += sRow[wid][k] * bf2f((uint)W1lds[k * 72 + lane]);
    Henc[(size_t)r * 64 + lane] = acc;
    HencB[(size_t)r * 64 + lane] = f2bf(acc);
}

// ---------------- decoder spmm + fused @W1T matvec + ELU --------------------
// gathers 64-wide bf16 Henc; S-row -> LDS -> D[r][2l..2l+1] bf16
__global__ __launch_bounds__(256) void spmm_dec_kernel(const int* __restrict__ rp,
                                                       const int2* __restrict__ eg,
                                                       const ushort* __restrict__ Hb,
                                                       const float* __restrict__ W1,
                                                       uint* __restrict__ Dh) {
    __shared__ ushort WTlds[64 * 136];          // W1T[k][m] = W1[m][k], padded 136
    __shared__ float sRow[4][64];
    for (int i = threadIdx.x; i < 8192; i += 256) {
        int k = i >> 7, m = i & 127;
        WTlds[k * 136 + m] = f2bf(W1[m * 64 + k]);
    }
    __syncthreads();
    int r = blockIdx.x * 4 + (threadIdx.x >> 6);
    int wid = threadIdx.x >> 6;
    int lane = threadIdx.x & 63;
    float a = 0.f;
    int j = rp[2 * r], E = rp[2 * r + 2];
    if (j < E) {
        int2 d[SPU]; ushort h[SPU];
#pragma unroll
        for (int u = 0; u < SPU; ++u) d[u] = eg[j + u];
#pragma unroll
        for (int u = 0; u < SPU; ++u) h[u] = Hb[(uint)d[u].x * 64u + lane];
        j += SPU;
        for (; j < E; j += SPU) {
            int2 dn[SPU]; ushort hn[SPU];
#pragma unroll
            for (int u = 0; u < SPU; ++u) dn[u] = eg[j + u];
#pragma unroll
            for (int u = 0; u < SPU; ++u) hn[u] = Hb[(uint)dn[u].x * 64u + lane];
#pragma unroll
            for (int u = 0; u < SPU; ++u)
                a += __int_as_float(d[u].y) * bf2f((uint)h[u]);
#pragma unroll
            for (int u = 0; u < SPU; ++u) { d[u] = dn[u]; h[u] = hn[u]; }
        }
#pragma unroll
        for (int u = 0; u < SPU; ++u)
            a += __int_as_float(d[u].y) * bf2f((uint)h[u]);
    }
    sRow[wid][lane] = a;
    asm volatile("s_waitcnt lgkmcnt(0)" ::: "memory");
    __builtin_amdgcn_sched_barrier(0);
    // D[r][m] = elu(sum_k S[k] * W1T[k][m]), m = 2*lane, 2*lane+1
    float d0 = 0.f, d1 = 0.f;
#pragma unroll 8
    for (int k = 0; k < 64; ++k) {
        float sv = sRow[wid][k];
        uint wv = *reinterpret_cast<const uint*>(&WTlds[k * 136 + 2 * lane]);
        d0 += sv * bf2f(wv & 0xffffu);
        d1 += sv * bf2f(wv >> 16);
    }
    d0 = d0 > 0.f ? d0 : expm1f(d0);
    d1 = d1 > 0.f ? d1 : expm1f(d1);
    Dh[(size_t)r * 64 + lane] = (uint)f2bf(d0) | ((uint)f2bf(d1) << 16);
}

// ---------------- reductions -----------------------------------------------
__global__ __launch_bounds__(256) void sqw_reduce_kernel(const float* __restrict__ W0,
                                                         const float* __restrict__ W1,
                                                         float* __restrict__ acc) {
    __shared__ float sm[4];
    float s = 0.f;
    for (int i = blockIdx.x * 256 + threadIdx.x; i < 40960; i += gridDim.x * 256) {
        float d = i < 32768 ? W0[i] : W1[i - 32768];
        s += d * d;
    }
#pragma unroll
    for (int off = 32; off > 0; off >>= 1) s += __shfl_down(s, off);
    int lane = threadIdx.x & 63, w = threadIdx.x >> 6;
    if (lane == 0) sm[w] = s;
    __syncthreads();
    if (threadIdx.x == 0) atomicAdd(acc, sm[0] + sm[1] + sm[2] + sm[3]);
}

__global__ __launch_bounds__(256) void partial_reduce_kernel(const float* __restrict__ p,
                                                             int n, float* __restrict__ acc) {
    __shared__ float sm[4];
    float s = 0.f;
    for (int i = threadIdx.x; i < n; i += 256) s += p[i];
#pragma unroll
    for (int off = 32; off > 0; off >>= 1) s += __shfl_down(s, off);
    int lane = threadIdx.x & 63, w = threadIdx.x >> 6;
    if (lane == 0) sm[w] = s;
    __syncthreads();
    if (threadIdx.x == 0) atomicAdd(acc, sm[0] + sm[1] + sm[2] + sm[3]);
}

__global__ void finalize_kernel(const float* __restrict__ acc, float* __restrict__ out) {
    out[0] = sqrtf(acc[0]) + 1e-4f * acc[1];
}

extern "C" void kernel_launch(void* const* d_in, const int* in_sizes, int n_in,
                              void* d_out, int out_size, void* d_ws, size_t ws_size,
                              hipStream_t stream) {
    const float* X    = (const float*)d_in[0];
    const float* W0   = (const float*)d_in[1];
    const float* W1   = (const float*)d_in[2];
    const float* v00  = (const float*)d_in[3];
    const float* v01  = (const float*)d_in[4];
    const float* pv00 = (const float*)d_in[5];
    const float* pv01 = (const float*)d_in[6];
    const int* rows   = (const int*)d_in[7];
    const int* cols   = (const int*)d_in[8];
    const int* prows  = (const int*)d_in[9];
    const int* pcols  = (const int*)d_in[10];

    float* out  = (float*)d_out;
    float* Henc = out + 1;                                  // N x 64 (misaligned base)
    float* Xrec = out + 1 + (size_t)N_NODES * 64;           // N x 256 (misaligned base)

    // scratch in dead X_ region [6400001, 32000001):
    ushort* bufAh  = (ushort*)(out + 6400004);              // N x 128 bf16 (H1)
    int*    ccol   = (int*)(out + 12800004);                // 4.8M int (padded CSR)
    int2*   eg     = (int2*)(out + 17600004);               // 4.8M int2
    ushort* HencB  = (ushort*)(out + 27200004);             // N x 64 bf16
    int*    deg    = (int*)(out + 28800004);                // 2N
    int*    cur    = deg + TOT;                             // 2N

    float* ws   = (float*)d_ws;
    ushort* bufBh = (ushort*)ws;                            // N x 128 bf16 (D)
    float* f1   = ws + (size_t)N_NODES * 128;
    float* f2   = f1 + N_NODES;
    float* pf1  = f2 + N_NODES;
    float* pf2  = pf1 + N_NODES;
    float* acc  = pf2 + N_NODES;                            // 4
    ushort* B1cm = (ushort*)(acc + 4);                      // 128 x 264
    ushort* B8cm = B1cm + 128 * 264;                        // 256 x 136
    int*   rp   = (int*)(B8cm + 256 * 136);                 // 2N+1
    int*   bsum = rp + TOT + 1;                             // SCAN_NB
    float* partial = (float*)(bsum + SCAN_NB);              // cdiv(n,128)

    const int n = N_NODES;
    const int EG = cdiv(N_EDGES, 256);
    const int EG2 = cdiv(2 * (long)N_EDGES, 256);

    // 0. weight prep (B1 + B8 only)
    prep_all_kernel<<<cdiv(65536, 256), 256, 0, stream>>>(W0, B1cm, B8cm);

    // 1. H1 = X @ W0 -> bufAh (bf16) + fused attention dots, MFMA
    gemm_mfma<256, 128, true, 2, false, false, true><<<cdiv(n, 128), 256, 0, stream>>>(
        X, B1cm, bufAh, nullptr, nullptr, nullptr,
        v00, v01, pv00, pv01, f1, f2, pf1, pf2, n);

    // zero deg+cur and acc
    hipMemsetAsync(deg, 0, 2 * (size_t)TOT * sizeof(int), stream);
    hipMemsetAsync(acc, 0, 4 * sizeof(float), stream);

    // 2. padded interleaved CSR (bucket = 2r+adj) + pre-scaled softmax weights
    hist2_kernel<<<EG2, 256, 0, stream>>>(rows, prows, deg);
    scan1_kernel<<<SCAN_NB, 256, 0, stream>>>(deg, bsum);
    scan3_kernel<<<SCAN_NB, 256, 0, stream>>>(deg, bsum, rp);
    scatter_kernel<<<EG, 256, 0, stream>>>(rows, cols, 0, rp, cur, ccol);
    scatter_kernel<<<EG, 256, 0, stream>>>(prows, pcols, 1, rp, cur, ccol);
    edgeval_kernel<<<cdiv(TOT, 16), 256, 0, stream>>>(rp, deg, ccol,
                                                      f1, f2, pf1, pf2, eg);

    // 3. encoder spmm + fused @W1: -> Henc (fp32, d_out) + HencB (bf16)
    spmm_enc_kernel<<<n / 4, 256, 0, stream>>>(rp, eg, bufAh, W1, Henc, HencB);

    // 4. decoder spmm on HencB + fused @W1T + ELU -> bufBh (bf16)
    spmm_dec_kernel<<<n / 4, 256, 0, stream>>>(rp, eg, HencB, W1, (uint*)bufBh);

    // 5. X_ = bufBh @ W0T -> Xrec + fused loss partials, MFMA
    gemm_mfma<128, 256, false, 0, false, true, false><<<cdiv(n, 128), 256, 0, stream>>>(
        bufBh, B8cm, Xrec, nullptr, X, partial,
        nullptr, nullptr, nullptr, nullptr, nullptr, nullptr, nullptr, nullptr, n);

    // 6. loss
    partial_reduce_kernel<<<1, 256, 0, stream>>>(partial, cdiv(n, 128), acc + 0);
    sqw_reduce_kernel<<<20, 256, 0, stream>>>(W0, W1, acc + 1);
    finalize_kernel<<<1, 1, 0, stream>>>(acc, out);
}

// Round 19
// 763.142 us; speedup vs baseline: 1.3902x; 1.3902x over previous
//
#include <hip/hip_runtime.h>
#include <math.h>

#define N_NODES 100000
#define N_EDGES 1600000
#define TOT (2 * N_NODES)            // CSR buckets: 2*row + adj
#define SCAN_NB 256
#define SCAN_CH 4                    // 256*256*4 = 262144 >= 2N+1

static inline int cdiv(long a, long b) { return (int)((a + b - 1) / b); }

typedef unsigned int uint;
typedef unsigned short ushort;
typedef __attribute__((ext_vector_type(8))) short short8v;   // 8 bf16 (4 VGPR)
typedef __attribute__((ext_vector_type(4))) float f32x4;

__device__ inline float bf2f(uint u) { return __uint_as_float(u << 16); }
__device__ inline ushort f2bf(float f) {
    uint u = __float_as_uint(f);
    uint r = ((u >> 16) & 1u) + 0x7fffu;   // RNE
    return (ushort)((u + r) >> 16);
}

// ---------------- MFMA bf16 GEMM: C[i,m] = sum_k A[i,k]*B[k,m] --------------
// ATTN (M==128 only): fused attention feature dots from fp32 accumulators.
template <int K, int M, bool AF32, int OUT, bool ELU, bool LOSS, bool ATTN>
__global__ __launch_bounds__(256) void gemm_mfma(const void* __restrict__ Av,
                                                 const ushort* __restrict__ Bcm,
                                                 void* __restrict__ Cv,
                                                 void* __restrict__ Cv2,
                                                 const float* __restrict__ Xref,
                                                 float* __restrict__ partial,
                                                 const float* __restrict__ va,
                                                 const float* __restrict__ vb,
                                                 const float* __restrict__ pva,
                                                 const float* __restrict__ pvb,
                                                 float* __restrict__ f1,
                                                 float* __restrict__ f2,
                                                 float* __restrict__ pf1,
                                                 float* __restrict__ pf2,
                                                 int nrows) {
    constexpr int BM = 128;
    constexpr int KP = K + 8;
    constexpr int NCT = M / 16;
    __shared__ ushort Blds[M * KP];
    __shared__ ushort Alds[BM * 32];
    const int w = threadIdx.x >> 6;
    const int l = threadIdx.x & 63;
    const int rowg = l & 15;
    const int kg = l >> 4;
    const int rbase = blockIdx.x * BM;
    {
        const uint4* src = reinterpret_cast<const uint4*>(Bcm);
        uint4* dst = reinterpret_cast<uint4*>(Blds);
        const int total = M * KP / 8;
        for (int i = threadIdx.x; i < total; i += 256) dst[i] = src[i];
    }
    f32x4 acc[2][NCT] = {};
    for (int k0 = 0; k0 < K; k0 += 32) {
        __syncthreads();
        int r = threadIdx.x >> 1;
        int kk = (threadIdx.x & 1) * 16;
        int rg = min(rbase + r, nrows - 1);
        if (AF32) {
            const float* A = (const float*)Av;
            const float4* src = reinterpret_cast<const float4*>(A + (size_t)rg * K + k0 + kk);
            ushort* dst = &Alds[r * 32 + kk];
#pragma unroll
            for (int q = 0; q < 4; ++q) {
                float4 v = src[q];
                dst[4 * q + 0] = f2bf(v.x); dst[4 * q + 1] = f2bf(v.y);
                dst[4 * q + 2] = f2bf(v.z); dst[4 * q + 3] = f2bf(v.w);
            }
        } else {
            const ushort* A = (const ushort*)Av;
            const uint4* src = reinterpret_cast<const uint4*>(A + (size_t)rg * K + k0 + kk);
            uint4* dst = reinterpret_cast<uint4*>(&Alds[r * 32 + kk]);
            dst[0] = src[0];
            dst[1] = src[1];
        }
        __syncthreads();
#pragma unroll
        for (int rt = 0; rt < 2; ++rt) {
            short8v af = *reinterpret_cast<const short8v*>(
                &Alds[(w * 32 + rt * 16 + rowg) * 32 + kg * 8]);
#pragma unroll
            for (int ct = 0; ct < NCT; ++ct) {
                short8v bf = *reinterpret_cast<const short8v*>(
                    &Blds[(ct * 16 + rowg) * KP + k0 + kg * 8]);
                acc[rt][ct] = __builtin_amdgcn_mfma_f32_16x16x32_bf16(
                    af, bf, acc[rt][ct], 0, 0, 0);
            }
        }
    }
    float lsum = 0.f;
#pragma unroll
    for (int rt = 0; rt < 2; ++rt) {
#pragma unroll
        for (int q = 0; q < 4; ++q) {
            int r = rbase + w * 32 + rt * 16 + kg * 4 + q;
            if (r >= nrows) continue;
#pragma unroll
            for (int ct = 0; ct < NCT; ++ct) {
                float o = acc[rt][ct][q];
                if (ELU) o = o > 0.f ? o : expm1f(o);
                int col = ct * 16 + rowg;
                if (OUT == 0 || OUT == 3) ((float*)Cv)[(size_t)r * M + col] = o;
                if (OUT == 2) ((ushort*)Cv)[(size_t)r * M + col] = f2bf(o);
                if (OUT == 3) ((ushort*)Cv2)[(size_t)r * M + col] = f2bf(o);
                if (LOSS) {
                    float d = o - Xref[(size_t)r * 256 + col];
                    lsum += d * d;
                }
            }
        }
    }
    if (ATTN) {
        float var[NCT], vbr[NCT], pvar[NCT], pvbr[NCT];
#pragma unroll
        for (int ct = 0; ct < NCT; ++ct) {
            int col = ct * 16 + rowg;
            var[ct] = va[col]; vbr[ct] = vb[col];
            pvar[ct] = pva[col]; pvbr[ct] = pvb[col];
        }
#pragma unroll
        for (int rt = 0; rt < 2; ++rt) {
#pragma unroll
            for (int q = 0; q < 4; ++q) {
                int r = rbase + w * 32 + rt * 16 + kg * 4 + q;
                float da = 0.f, db = 0.f, dpa = 0.f, dpb = 0.f;
#pragma unroll
                for (int ct = 0; ct < NCT; ++ct) {
                    float o = acc[rt][ct][q];
                    da += o * var[ct]; db += o * vbr[ct];
                    dpa += o * pvar[ct]; dpb += o * pvbr[ct];
                }
#pragma unroll
                for (int m = 1; m < 16; m <<= 1) {
                    da += __shfl_xor(da, m); db += __shfl_xor(db, m);
                    dpa += __shfl_xor(dpa, m); dpb += __shfl_xor(dpb, m);
                }
                if (rowg == 0 && r < nrows) {
                    f1[r] = da; f2[r] = db; pf1[r] = dpa; pf2[r] = dpb;
                }
            }
        }
    }
    if (LOSS) {
        __shared__ float smRed[4];
#pragma unroll
        for (int off = 32; off > 0; off >>= 1) lsum += __shfl_down(lsum, off);
        __syncthreads();
        if (l == 0) smRed[w] = lsum;
        __syncthreads();
        if (threadIdx.x == 0)
            partial[blockIdx.x] = smRed[0] + smRed[1] + smRed[2] + smRed[3];
    }
}

// ---------------- weight prep: B1 + B8 only ---------------------------------
__global__ __launch_bounds__(256) void prep_all_kernel(const float* __restrict__ W0,
                                                       ushort* __restrict__ B1,
                                                       ushort* __restrict__ B8) {
    int i = blockIdx.x * 256 + threadIdx.x;
    if (i < 32768) {                            // B1[m][k] = W0[k][m], K=256 M=128
        int k = i / 128, m = i - k * 128;
        B1[m * 264 + k] = f2bf(W0[i]);
    } else if (i < 65536) {                     // B8[m][k] = W0[m][k], K=128 M=256
        int j = i - 32768;
        int m = j / 128, k = j - m * 128;
        B8[m * 136 + k] = f2bf(W0[j]);
    }
}

// ---------------- CSR build: bucket = 2*row + adj, rows padded to x8 --------
__global__ __launch_bounds__(256) void hist2_kernel(const int* __restrict__ rows,
                                                    const int* __restrict__ prows,
                                                    int* __restrict__ deg) {
    int e = blockIdx.x * 256 + threadIdx.x;
    if (e >= 2 * N_EDGES) return;
    int b = e < N_EDGES ? rows[e] * 2 : prows[e - N_EDGES] * 2 + 1;
    atomicAdd(&deg[b], 1);
}

__device__ inline int pad8(int d) { return (d + 7) & ~7; }

__global__ __launch_bounds__(256) void scan1_kernel(const int* __restrict__ deg,
                                                    int* __restrict__ bsum) {
    __shared__ int sm[256];
    int base = (blockIdx.x * 256 + threadIdx.x) * SCAN_CH;
    int s = 0;
#pragma unroll
    for (int i = 0; i < SCAN_CH; ++i) {
        int idx = base + i;
        if (idx < TOT) s += pad8(deg[idx]);
    }
    sm[threadIdx.x] = s;
    __syncthreads();
    for (int off = 128; off > 0; off >>= 1) {
        if (threadIdx.x < off) sm[threadIdx.x] += sm[threadIdx.x + off];
        __syncthreads();
    }
    if (threadIdx.x == 0) bsum[blockIdx.x] = sm[0];
}

__global__ __launch_bounds__(256) void scan3_kernel(const int* __restrict__ deg,
                                                    const int* __restrict__ bsum,
                                                    int* __restrict__ rp) {
    __shared__ int sm[256];
    __shared__ int base0;
    if (threadIdx.x == 0) {
        int run = 0;
        for (int i = 0; i < blockIdx.x; ++i) run += bsum[i];
        base0 = run;
    }
    int base = (blockIdx.x * 256 + threadIdx.x) * SCAN_CH;
    int s = 0;
#pragma unroll
    for (int i = 0; i < SCAN_CH; ++i) {
        int idx = base + i;
        if (idx < TOT) s += pad8(deg[idx]);
    }
    sm[threadIdx.x] = s;
    __syncthreads();
    if (threadIdx.x == 0) {
        int run = base0;
        for (int t = 0; t < 256; ++t) { int tmp = sm[t]; sm[t] = run; run += tmp; }
    }
    __syncthreads();
    int off = sm[threadIdx.x];
#pragma unroll
    for (int i = 0; i < SCAN_CH; ++i) {
        int idx = base + i;
        if (idx < TOT) { rp[idx] = off; off += pad8(deg[idx]); }
        else if (idx == TOT) rp[idx] = off;
    }
}

__global__ __launch_bounds__(256) void scatter_kernel(const int* __restrict__ rlist,
                                                      const int* __restrict__ clist,
                                                      int adj,
                                                      const int* __restrict__ rp,
                                                      int* __restrict__ cur,
                                                      int* __restrict__ ccol) {
    int e = blockIdx.x * 256 + threadIdx.x;
    if (e >= N_EDGES) return;
    int b = rlist[e] * 2 + adj;
    int pos = rp[b] + atomicAdd(&cur[b], 1);
    ccol[pos] = clist[e];
}

// ---------------- edge weights: pre-normalized+scaled; pad slots = {0,0} ----
__global__ __launch_bounds__(256) void edgeval_kernel(const int* __restrict__ rp,
                                                      const int* __restrict__ deg,
                                                      const int* __restrict__ ccol,
                                                      const float* __restrict__ f1,
                                                      const float* __restrict__ f2,
                                                      const float* __restrict__ pf1,
                                                      const float* __restrict__ pf2,
                                                      int2* __restrict__ eg) {
    int b = blockIdx.x * 16 + (threadIdx.x >> 4);
    int sl = threadIdx.x & 15;
    int adj = b & 1, r = b >> 1;
    float f1r = adj ? pf1[r] : f1[r];
    const float* f2t = adj ? pf2 : f2;
    float scale = adj ? 0.8f : 0.2f;
    int j0 = rp[b];
    int realend = j0 + deg[b];
    int pend = rp[b + 1];
    float s = 0.f;
    for (int j = j0 + sl; j < realend; j += 16)
        s += __expf(f1r + f2t[ccol[j]]);
#pragma unroll
    for (int off = 8; off > 0; off >>= 1) s += __shfl_xor(s, off);
    float inv = s > 0.f ? scale / s : 0.f;
    for (int j = j0 + sl; j < pend; j += 16) {
        if (j < realend) {
            int c = ccol[j];
            float wv = __expf(f1r + f2t[c]) * inv;
            eg[j] = make_int2(c, __float_as_int(wv));
        } else {
            eg[j] = make_int2(0, 0);
        }
    }
}

// ---------------- encoder spmm + fused @W1 matvec ---------------------------
#define SPU 8
__global__ __launch_bounds__(256) void spmm_enc_kernel(const int* __restrict__ rp,
                                                       const int2* __restrict__ eg,
                                                       const ushort* __restrict__ Hb,
                                                       const float* __restrict__ W1,
                                                       float* __restrict__ Henc,
                                                       ushort* __restrict__ HencB) {
    __shared__ ushort W1lds[128 * 72];          // W1[k][m] bf16, padded 72
    __shared__ float sRow[4][128];
    for (int i = threadIdx.x; i < 8192; i += 256) {
        int k = i >> 6, m = i & 63;             // coalesced read W1[i]
        W1lds[k * 72 + m] = f2bf(W1[i]);
    }
    __syncthreads();
    int r = blockIdx.x * 4 + (threadIdx.x >> 6);
    int wid = threadIdx.x >> 6;
    int lane = threadIdx.x & 63;
    const uint* Hu = reinterpret_cast<const uint*>(Hb);
    float a0 = 0.f, a1 = 0.f;
    int j = rp[2 * r], E = rp[2 * r + 2];       // wave-uniform bounds
    if (j < E) {
        int2 d[SPU]; uint h[SPU];
#pragma unroll
        for (int u = 0; u < SPU; ++u) d[u] = eg[j + u];
#pragma unroll
        for (int u = 0; u < SPU; ++u) h[u] = Hu[(uint)d[u].x * 64u + lane];
        j += SPU;
        for (; j < E; j += SPU) {
            int2 dn[SPU]; uint hn[SPU];
#pragma unroll
            for (int u = 0; u < SPU; ++u) dn[u] = eg[j + u];
#pragma unroll
            for (int u = 0; u < SPU; ++u) hn[u] = Hu[(uint)dn[u].x * 64u + lane];
#pragma unroll
            for (int u = 0; u < SPU; ++u) {
                float v = __int_as_float(d[u].y);
                a0 += v * bf2f(h[u] & 0xffffu);
                a1 += v * bf2f(h[u] >> 16);
            }
#pragma unroll
            for (int u = 0; u < SPU; ++u) { d[u] = dn[u]; h[u] = hn[u]; }
        }
#pragma unroll
        for (int u = 0; u < SPU; ++u) {
            float v = __int_as_float(d[u].y);
            a0 += v * bf2f(h[u] & 0xffffu);
            a1 += v * bf2f(h[u] >> 16);
        }
    }
    a0 = a0 > 0.f ? a0 : expm1f(a0);
    a1 = a1 > 0.f ? a1 : expm1f(a1);
    sRow[wid][2 * lane] = a0;
    sRow[wid][2 * lane + 1] = a1;
    asm volatile("s_waitcnt lgkmcnt(0)" ::: "memory");
    __builtin_amdgcn_sched_barrier(0);
    float acc = 0.f;
#pragma unroll 8
    for (int k = 0; k < 128; ++k)
        acc += sRow[wid][k] * bf2f((uint)W1lds[k * 72 + lane]);
    Henc[(size_t)r * 64 + lane] = acc;
    HencB[(size_t)r * 64 + lane] = f2bf(acc);
}

// ---------------- decoder spmm + fused @W1T matvec + ELU --------------------
__global__ __launch_bounds__(256) void spmm_dec_kernel(const int* __restrict__ rp,
                                                       const int2* __restrict__ eg,
                                                       const ushort* __restrict__ Hb,
                                                       const float* __restrict__ W1,
                                                       uint* __restrict__ Dh) {
    __shared__ ushort WTlds[64 * 136];          // W1T[k][m] = W1[m][k], padded 136
    __shared__ float sRow[4][64];
    // FIX vs r18: coalesced GLOBAL read (W1[i] linear), transposed LDS write.
    for (int i = threadIdx.x; i < 8192; i += 256) {
        int m = i >> 6, k = i & 63;             // W1[i] = W1[m][k]
        WTlds[k * 136 + m] = f2bf(W1[i]);
    }
    __syncthreads();
    int r = blockIdx.x * 4 + (threadIdx.x >> 6);
    int wid = threadIdx.x >> 6;
    int lane = threadIdx.x & 63;
    float a = 0.f;
    int j = rp[2 * r], E = rp[2 * r + 2];
    if (j < E) {
        int2 d[SPU]; ushort h[SPU];
#pragma unroll
        for (int u = 0; u < SPU; ++u) d[u] = eg[j + u];
#pragma unroll
        for (int u = 0; u < SPU; ++u) h[u] = Hb[(uint)d[u].x * 64u + lane];
        j += SPU;
        for (; j < E; j += SPU) {
            int2 dn[SPU]; ushort hn[SPU];
#pragma unroll
            for (int u = 0; u < SPU; ++u) dn[u] = eg[j + u];
#pragma unroll
            for (int u = 0; u < SPU; ++u) hn[u] = Hb[(uint)dn[u].x * 64u + lane];
#pragma unroll
            for (int u = 0; u < SPU; ++u)
                a += __int_as_float(d[u].y) * bf2f((uint)h[u]);
#pragma unroll
            for (int u = 0; u < SPU; ++u) { d[u] = dn[u]; h[u] = hn[u]; }
        }
#pragma unroll
        for (int u = 0; u < SPU; ++u)
            a += __int_as_float(d[u].y) * bf2f((uint)h[u]);
    }
    sRow[wid][lane] = a;
    asm volatile("s_waitcnt lgkmcnt(0)" ::: "memory");
    __builtin_amdgcn_sched_barrier(0);
    float d0 = 0.f, d1 = 0.f;
#pragma unroll 8
    for (int k = 0; k < 64; ++k) {
        float sv = sRow[wid][k];
        uint wv = *reinterpret_cast<const uint*>(&WTlds[k * 136 + 2 * lane]);
        d0 += sv * bf2f(wv & 0xffffu);
        d1 += sv * bf2f(wv >> 16);
    }
    d0 = d0 > 0.f ? d0 : expm1f(d0);
    d1 = d1 > 0.f ? d1 : expm1f(d1);
    Dh[(size_t)r * 64 + lane] = (uint)f2bf(d0) | ((uint)f2bf(d1) << 16);
}

// ---------------- reductions -----------------------------------------------
__global__ __launch_bounds__(256) void sqw_reduce_kernel(const float* __restrict__ W0,
                                                         const float* __restrict__ W1,
                                                         float* __restrict__ acc) {
    __shared__ float sm[4];
    float s = 0.f;
    for (int i = blockIdx.x * 256 + threadIdx.x; i < 40960; i += gridDim.x * 256) {
        float d = i < 32768 ? W0[i] : W1[i - 32768];
        s += d * d;
    }
#pragma unroll
    for (int off = 32; off > 0; off >>= 1) s += __shfl_down(s, off);
    int lane = threadIdx.x & 63, w = threadIdx.x >> 6;
    if (lane == 0) sm[w] = s;
    __syncthreads();
    if (threadIdx.x == 0) atomicAdd(acc, sm[0] + sm[1] + sm[2] + sm[3]);
}

__global__ __launch_bounds__(256) void partial_reduce_kernel(const float* __restrict__ p,
                                                             int n, float* __restrict__ acc) {
    __shared__ float sm[4];
    float s = 0.f;
    for (int i = threadIdx.x; i < n; i += 256) s += p[i];
#pragma unroll
    for (int off = 32; off > 0; off >>= 1) s += __shfl_down(s, off);
    int lane = threadIdx.x & 63, w = threadIdx.x >> 6;
    if (lane == 0) sm[w] = s;
    __syncthreads();
    if (threadIdx.x == 0) atomicAdd(acc, sm[0] + sm[1] + sm[2] + sm[3]);
}

__global__ void finalize_kernel(const float* __restrict__ acc, float* __restrict__ out) {
    out[0] = sqrtf(acc[0]) + 1e-4f * acc[1];
}

extern "C" void kernel_launch(void* const* d_in, const int* in_sizes, int n_in,
                              void* d_out, int out_size, void* d_ws, size_t ws_size,
                              hipStream_t stream) {
    const float* X    = (const float*)d_in[0];
    const float* W0   = (const float*)d_in[1];
    const float* W1   = (const float*)d_in[2];
    const float* v00  = (const float*)d_in[3];
    const float* v01  = (const float*)d_in[4];
    const float* pv00 = (const float*)d_in[5];
    const float* pv01 = (const float*)d_in[6];
    const int* rows   = (const int*)d_in[7];
    const int* cols   = (const int*)d_in[8];
    const int* prows  = (const int*)d_in[9];
    const int* pcols  = (const int*)d_in[10];

    float* out  = (float*)d_out;
    float* Henc = out + 1;                                  // N x 64 (misaligned base)
    float* Xrec = out + 1 + (size_t)N_NODES * 64;           // N x 256 (misaligned base)

    // scratch in dead X_ region [6400001, 32000001):
    ushort* bufAh  = (ushort*)(out + 6400004);              // N x 128 bf16 (H1)
    int*    ccol   = (int*)(out + 12800004);                // 4.8M int (padded CSR)
    int2*   eg     = (int2*)(out + 17600004);               // 4.8M int2
    ushort* HencB  = (ushort*)(out + 27200004);             // N x 64 bf16
    int*    deg    = (int*)(out + 28800004);                // 2N
    int*    cur    = deg + TOT;                             // 2N

    float* ws   = (float*)d_ws;
    ushort* bufBh = (ushort*)ws;                            // N x 128 bf16 (D)
    float* f1   = ws + (size_t)N_NODES * 128;
    float* f2   = f1 + N_NODES;
    float* pf1  = f2 + N_NODES;
    float* pf2  = pf1 + N_NODES;
    float* acc  = pf2 + N_NODES;                            // 4
    ushort* B1cm = (ushort*)(acc + 4);                      // 128 x 264
    ushort* B8cm = B1cm + 128 * 264;                        // 256 x 136
    int*   rp   = (int*)(B8cm + 256 * 136);                 // 2N+1
    int*   bsum = rp + TOT + 1;                             // SCAN_NB
    float* partial = (float*)(bsum + SCAN_NB);              // cdiv(n,128)

    const int n = N_NODES;
    const int EG = cdiv(N_EDGES, 256);
    const int EG2 = cdiv(2 * (long)N_EDGES, 256);

    // 0. weight prep (B1 + B8 only)
    prep_all_kernel<<<cdiv(65536, 256), 256, 0, stream>>>(W0, B1cm, B8cm);

    // 1. H1 = X @ W0 -> bufAh (bf16) + fused attention dots, MFMA
    gemm_mfma<256, 128, true, 2, false, false, true><<<cdiv(n, 128), 256, 0, stream>>>(
        X, B1cm, bufAh, nullptr, nullptr, nullptr,
        v00, v01, pv00, pv01, f1, f2, pf1, pf2, n);

    // zero deg+cur and acc
    hipMemsetAsync(deg, 0, 2 * (size_t)TOT * sizeof(int), stream);
    hipMemsetAsync(acc, 0, 4 * sizeof(float), stream);

    // 2. padded interleaved CSR (bucket = 2r+adj) + pre-scaled softmax weights
    hist2_kernel<<<EG2, 256, 0, stream>>>(rows, prows, deg);
    scan1_kernel<<<SCAN_NB, 256, 0, stream>>>(deg, bsum);
    scan3_kernel<<<SCAN_NB, 256, 0, stream>>>(deg, bsum, rp);
    scatter_kernel<<<EG, 256, 0, stream>>>(rows, cols, 0, rp, cur, ccol);
    scatter_kernel<<<EG, 256, 0, stream>>>(prows, pcols, 1, rp, cur, ccol);
    edgeval_kernel<<<cdiv(TOT, 16), 256, 0, stream>>>(rp, deg, ccol,
                                                      f1, f2, pf1, pf2, eg);

    // 3. encoder spmm + fused @W1: -> Henc (fp32, d_out) + HencB (bf16)
    spmm_enc_kernel<<<n / 4, 256, 0, stream>>>(rp, eg, bufAh, W1, Henc, HencB);

    // 4. decoder spmm on HencB + fused @W1T + ELU -> bufBh (bf16)
    spmm_dec_kernel<<<n / 4, 256, 0, stream>>>(rp, eg, HencB, W1, (uint*)bufBh);

    // 5. X_ = bufBh @ W0T -> Xrec + fused loss partials, MFMA
    gemm_mfma<128, 256, false, 0, false, true, false><<<cdiv(n, 128), 256, 0, stream>>>(
        bufBh, B8cm, Xrec, nullptr, X, partial,
        nullptr, nullptr, nullptr, nullptr, nullptr, nullptr, nullptr, nullptr, n);

    // 6. loss
    partial_reduce_kernel<<<1, 256, 0, stream>>>(partial, cdiv(n, 128), acc + 0);
    sqw_reduce_kernel<<<20, 256, 0, stream>>>(W0, W1, acc + 1);
    finalize_kernel<<<1, 1, 0, stream>>>(acc, out);
}

// Round 20
// 762.292 us; speedup vs baseline: 1.3917x; 1.0011x over previous
//
#include <hip/hip_runtime.h>
#include <math.h>

#define N_NODES 100000
#define N_EDGES 1600000
#define TOT (2 * N_NODES)            // CSR buckets: 2*row + adj
#define SCAN_NB 256
#define SCAN_CH 4                    // 256*256*4 = 262144 >= 2N+1

static inline int cdiv(long a, long b) { return (int)((a + b - 1) / b); }

typedef unsigned int uint;
typedef unsigned short ushort;
typedef __attribute__((ext_vector_type(8))) short short8v;   // 8 bf16 (4 VGPR)
typedef __attribute__((ext_vector_type(4))) float f32x4;

__device__ inline float bf2f(uint u) { return __uint_as_float(u << 16); }
__device__ inline ushort f2bf(float f) {
    uint u = __float_as_uint(f);
    uint r = ((u >> 16) & 1u) + 0x7fffu;   // RNE
    return (ushort)((u + r) >> 16);
}

// ---------------- MFMA bf16 GEMM: C[i,m] = sum_k A[i,k]*B[k,m] --------------
// ATTN (M==128 only): fused attention feature dots from fp32 accumulators.
template <int K, int M, bool AF32, int OUT, bool ELU, bool LOSS, bool ATTN>
__global__ __launch_bounds__(256) void gemm_mfma(const void* __restrict__ Av,
                                                 const ushort* __restrict__ Bcm,
                                                 void* __restrict__ Cv,
                                                 void* __restrict__ Cv2,
                                                 const float* __restrict__ Xref,
                                                 float* __restrict__ partial,
                                                 const float* __restrict__ va,
                                                 const float* __restrict__ vb,
                                                 const float* __restrict__ pva,
                                                 const float* __restrict__ pvb,
                                                 float* __restrict__ f1,
                                                 float* __restrict__ f2,
                                                 float* __restrict__ pf1,
                                                 float* __restrict__ pf2,
                                                 int nrows) {
    constexpr int BM = 128;
    constexpr int KP = K + 8;
    constexpr int NCT = M / 16;
    __shared__ ushort Blds[M * KP];
    __shared__ ushort Alds[BM * 32];
    const int w = threadIdx.x >> 6;
    const int l = threadIdx.x & 63;
    const int rowg = l & 15;
    const int kg = l >> 4;
    const int rbase = blockIdx.x * BM;
    {
        const uint4* src = reinterpret_cast<const uint4*>(Bcm);
        uint4* dst = reinterpret_cast<uint4*>(Blds);
        const int total = M * KP / 8;
        for (int i = threadIdx.x; i < total; i += 256) dst[i] = src[i];
    }
    f32x4 acc[2][NCT] = {};
    for (int k0 = 0; k0 < K; k0 += 32) {
        __syncthreads();
        int r = threadIdx.x >> 1;
        int kk = (threadIdx.x & 1) * 16;
        int rg = min(rbase + r, nrows - 1);
        if (AF32) {
            const float* A = (const float*)Av;
            const float4* src = reinterpret_cast<const float4*>(A + (size_t)rg * K + k0 + kk);
            ushort* dst = &Alds[r * 32 + kk];
#pragma unroll
            for (int q = 0; q < 4; ++q) {
                float4 v = src[q];
                dst[4 * q + 0] = f2bf(v.x); dst[4 * q + 1] = f2bf(v.y);
                dst[4 * q + 2] = f2bf(v.z); dst[4 * q + 3] = f2bf(v.w);
            }
        } else {
            const ushort* A = (const ushort*)Av;
            const uint4* src = reinterpret_cast<const uint4*>(A + (size_t)rg * K + k0 + kk);
            uint4* dst = reinterpret_cast<uint4*>(&Alds[r * 32 + kk]);
            dst[0] = src[0];
            dst[1] = src[1];
        }
        __syncthreads();
#pragma unroll
        for (int rt = 0; rt < 2; ++rt) {
            short8v af = *reinterpret_cast<const short8v*>(
                &Alds[(w * 32 + rt * 16 + rowg) * 32 + kg * 8]);
#pragma unroll
            for (int ct = 0; ct < NCT; ++ct) {
                short8v bf = *reinterpret_cast<const short8v*>(
                    &Blds[(ct * 16 + rowg) * KP + k0 + kg * 8]);
                acc[rt][ct] = __builtin_amdgcn_mfma_f32_16x16x32_bf16(
                    af, bf, acc[rt][ct], 0, 0, 0);
            }
        }
    }
    float lsum = 0.f;
#pragma unroll
    for (int rt = 0; rt < 2; ++rt) {
#pragma unroll
        for (int q = 0; q < 4; ++q) {
            int r = rbase + w * 32 + rt * 16 + kg * 4 + q;
            if (r >= nrows) continue;
#pragma unroll
            for (int ct = 0; ct < NCT; ++ct) {
                float o = acc[rt][ct][q];
                if (ELU) o = o > 0.f ? o : expm1f(o);
                int col = ct * 16 + rowg;
                if (OUT == 0 || OUT == 3) ((float*)Cv)[(size_t)r * M + col] = o;
                if (OUT == 2) ((ushort*)Cv)[(size_t)r * M + col] = f2bf(o);
                if (OUT == 3) ((ushort*)Cv2)[(size_t)r * M + col] = f2bf(o);
                if (LOSS) {
                    float d = o - Xref[(size_t)r * 256 + col];
                    lsum += d * d;
                }
            }
        }
    }
    if (ATTN) {
        float var[NCT], vbr[NCT], pvar[NCT], pvbr[NCT];
#pragma unroll
        for (int ct = 0; ct < NCT; ++ct) {
            int col = ct * 16 + rowg;
            var[ct] = va[col]; vbr[ct] = vb[col];
            pvar[ct] = pva[col]; pvbr[ct] = pvb[col];
        }
#pragma unroll
        for (int rt = 0; rt < 2; ++rt) {
#pragma unroll
            for (int q = 0; q < 4; ++q) {
                int r = rbase + w * 32 + rt * 16 + kg * 4 + q;
                float da = 0.f, db = 0.f, dpa = 0.f, dpb = 0.f;
#pragma unroll
                for (int ct = 0; ct < NCT; ++ct) {
                    float o = acc[rt][ct][q];
                    da += o * var[ct]; db += o * vbr[ct];
                    dpa += o * pvar[ct]; dpb += o * pvbr[ct];
                }
#pragma unroll
                for (int m = 1; m < 16; m <<= 1) {
                    da += __shfl_xor(da, m); db += __shfl_xor(db, m);
                    dpa += __shfl_xor(dpa, m); dpb += __shfl_xor(dpb, m);
                }
                if (rowg == 0 && r < nrows) {
                    f1[r] = da; f2[r] = db; pf1[r] = dpa; pf2[r] = dpb;
                }
            }
        }
    }
    if (LOSS) {
        __shared__ float smRed[4];
#pragma unroll
        for (int off = 32; off > 0; off >>= 1) lsum += __shfl_down(lsum, off);
        __syncthreads();
        if (l == 0) smRed[w] = lsum;
        __syncthreads();
        if (threadIdx.x == 0)
            partial[blockIdx.x] = smRed[0] + smRed[1] + smRed[2] + smRed[3];
    }
}

// ---------------- weight prep: B1 + B8 + B7 ---------------------------------
__global__ __launch_bounds__(256) void prep_all_kernel(const float* __restrict__ W0,
                                                       const float* __restrict__ W1,
                                                       ushort* __restrict__ B1,
                                                       ushort* __restrict__ B7,
                                                       ushort* __restrict__ B8) {
    int i = blockIdx.x * 256 + threadIdx.x;
    if (i < 32768) {                            // B1[m][k] = W0[k][m], K=256 M=128
        int k = i / 128, m = i - k * 128;
        B1[m * 264 + k] = f2bf(W0[i]);
    } else if (i < 65536) {                     // B8[m][k] = W0[m][k], K=128 M=256
        int j = i - 32768;
        int m = j / 128, k = j - m * 128;
        B8[m * 136 + k] = f2bf(W0[j]);
    } else if (i < 73728) {                     // B7[m][k] = W1[m][k], K=64 M=128
        int j = i - 65536;
        int m = j / 64, k = j - m * 64;
        B7[m * 72 + k] = f2bf(W1[j]);
    }
}

// ---------------- CSR build: bucket = 2*row + adj, rows padded to x8 --------
__global__ __launch_bounds__(256) void hist2_kernel(const int* __restrict__ rows,
                                                    const int* __restrict__ prows,
                                                    int* __restrict__ deg) {
    int e = blockIdx.x * 256 + threadIdx.x;
    if (e >= 2 * N_EDGES) return;
    int b = e < N_EDGES ? rows[e] * 2 : prows[e - N_EDGES] * 2 + 1;
    atomicAdd(&deg[b], 1);
}

__device__ inline int pad8(int d) { return (d + 7) & ~7; }

__global__ __launch_bounds__(256) void scan1_kernel(const int* __restrict__ deg,
                                                    int* __restrict__ bsum) {
    __shared__ int sm[256];
    int base = (blockIdx.x * 256 + threadIdx.x) * SCAN_CH;
    int s = 0;
#pragma unroll
    for (int i = 0; i < SCAN_CH; ++i) {
        int idx = base + i;
        if (idx < TOT) s += pad8(deg[idx]);
    }
    sm[threadIdx.x] = s;
    __syncthreads();
    for (int off = 128; off > 0; off >>= 1) {
        if (threadIdx.x < off) sm[threadIdx.x] += sm[threadIdx.x + off];
        __syncthreads();
    }
    if (threadIdx.x == 0) bsum[blockIdx.x] = sm[0];
}

__global__ __launch_bounds__(256) void scan3_kernel(const int* __restrict__ deg,
                                                    const int* __restrict__ bsum,
                                                    int* __restrict__ rp) {
    __shared__ int sm[256];
    __shared__ int base0;
    if (threadIdx.x == 0) {
        int run = 0;
        for (int i = 0; i < blockIdx.x; ++i) run += bsum[i];
        base0 = run;
    }
    int base = (blockIdx.x * 256 + threadIdx.x) * SCAN_CH;
    int s = 0;
#pragma unroll
    for (int i = 0; i < SCAN_CH; ++i) {
        int idx = base + i;
        if (idx < TOT) s += pad8(deg[idx]);
    }
    sm[threadIdx.x] = s;
    __syncthreads();
    if (threadIdx.x == 0) {
        int run = base0;
        for (int t = 0; t < 256; ++t) { int tmp = sm[t]; sm[t] = run; run += tmp; }
    }
    __syncthreads();
    int off = sm[threadIdx.x];
#pragma unroll
    for (int i = 0; i < SCAN_CH; ++i) {
        int idx = base + i;
        if (idx < TOT) { rp[idx] = off; off += pad8(deg[idx]); }
        else if (idx == TOT) rp[idx] = off;
    }
}

__global__ __launch_bounds__(256) void scatter_kernel(const int* __restrict__ rlist,
                                                      const int* __restrict__ clist,
                                                      int adj,
                                                      const int* __restrict__ rp,
                                                      int* __restrict__ cur,
                                                      int* __restrict__ ccol) {
    int e = blockIdx.x * 256 + threadIdx.x;
    if (e >= N_EDGES) return;
    int b = rlist[e] * 2 + adj;
    int pos = rp[b] + atomicAdd(&cur[b], 1);
    ccol[pos] = clist[e];
}

// ---------------- edge weights: pre-normalized+scaled; pad slots = {0,0} ----
__global__ __launch_bounds__(256) void edgeval_kernel(const int* __restrict__ rp,
                                                      const int* __restrict__ deg,
                                                      const int* __restrict__ ccol,
                                                      const float* __restrict__ f1,
                                                      const float* __restrict__ f2,
                                                      const float* __restrict__ pf1,
                                                      const float* __restrict__ pf2,
                                                      int2* __restrict__ eg) {
    int b = blockIdx.x * 16 + (threadIdx.x >> 4);
    int sl = threadIdx.x & 15;
    int adj = b & 1, r = b >> 1;
    float f1r = adj ? pf1[r] : f1[r];
    const float* f2t = adj ? pf2 : f2;
    float scale = adj ? 0.8f : 0.2f;
    int j0 = rp[b];
    int realend = j0 + deg[b];
    int pend = rp[b + 1];
    float s = 0.f;
    for (int j = j0 + sl; j < realend; j += 16)
        s += __expf(f1r + f2t[ccol[j]]);
#pragma unroll
    for (int off = 8; off > 0; off >>= 1) s += __shfl_xor(s, off);
    float inv = s > 0.f ? scale / s : 0.f;
    for (int j = j0 + sl; j < pend; j += 16) {
        if (j < realend) {
            int c = ccol[j];
            float wv = __expf(f1r + f2t[c]) * inv;
            eg[j] = make_int2(c, __float_as_int(wv));
        } else {
            eg[j] = make_int2(0, 0);
        }
    }
}

// ---------------- encoder spmm + fused @W1 matvec (net win, kept) -----------
#define SPU 8
__global__ __launch_bounds__(256) void spmm_enc_kernel(const int* __restrict__ rp,
                                                       const int2* __restrict__ eg,
                                                       const ushort* __restrict__ Hb,
                                                       const float* __restrict__ W1,
                                                       float* __restrict__ Henc,
                                                       ushort* __restrict__ HencB) {
    __shared__ ushort W1lds[128 * 72];          // W1[k][m] bf16, padded 72
    __shared__ float sRow[4][128];
    for (int i = threadIdx.x; i < 8192; i += 256) {
        int k = i >> 6, m = i & 63;             // coalesced read W1[i]
        W1lds[k * 72 + m] = f2bf(W1[i]);
    }
    __syncthreads();
    int r = blockIdx.x * 4 + (threadIdx.x >> 6);
    int wid = threadIdx.x >> 6;
    int lane = threadIdx.x & 63;
    const uint* Hu = reinterpret_cast<const uint*>(Hb);
    float a0 = 0.f, a1 = 0.f;
    int j = rp[2 * r], E = rp[2 * r + 2];       // wave-uniform bounds
    if (j < E) {
        int2 d[SPU]; uint h[SPU];
#pragma unroll
        for (int u = 0; u < SPU; ++u) d[u] = eg[j + u];
#pragma unroll
        for (int u = 0; u < SPU; ++u) h[u] = Hu[(uint)d[u].x * 64u + lane];
        j += SPU;
        for (; j < E; j += SPU) {
            int2 dn[SPU]; uint hn[SPU];
#pragma unroll
            for (int u = 0; u < SPU; ++u) dn[u] = eg[j + u];
#pragma unroll
            for (int u = 0; u < SPU; ++u) hn[u] = Hu[(uint)dn[u].x * 64u + lane];
#pragma unroll
            for (int u = 0; u < SPU; ++u) {
                float v = __int_as_float(d[u].y);
                a0 += v * bf2f(h[u] & 0xffffu);
                a1 += v * bf2f(h[u] >> 16);
            }
#pragma unroll
            for (int u = 0; u < SPU; ++u) { d[u] = dn[u]; h[u] = hn[u]; }
        }
#pragma unroll
        for (int u = 0; u < SPU; ++u) {
            float v = __int_as_float(d[u].y);
            a0 += v * bf2f(h[u] & 0xffffu);
            a1 += v * bf2f(h[u] >> 16);
        }
    }
    a0 = a0 > 0.f ? a0 : expm1f(a0);
    a1 = a1 > 0.f ? a1 : expm1f(a1);
    sRow[wid][2 * lane] = a0;
    sRow[wid][2 * lane + 1] = a1;
    asm volatile("s_waitcnt lgkmcnt(0)" ::: "memory");
    __builtin_amdgcn_sched_barrier(0);
    float acc = 0.f;
#pragma unroll 8
    for (int k = 0; k < 128; ++k)
        acc += sRow[wid][k] * bf2f((uint)W1lds[k * 72 + lane]);
    Henc[(size_t)r * 64 + lane] = acc;
    HencB[(size_t)r * 64 + lane] = f2bf(acc);
}

// ---------------- decoder spmm (lean, r17 form): emits bf16 S ---------------
__global__ __launch_bounds__(256) void spmm64_fused_kernel(const int* __restrict__ rp,
                                                           const int2* __restrict__ eg,
                                                           const ushort* __restrict__ Hb,
                                                           ushort* __restrict__ Sh) {
    int r = blockIdx.x * 4 + (threadIdx.x >> 6);
    int lane = threadIdx.x & 63;
    float a = 0.f;
    int j = rp[2 * r], E = rp[2 * r + 2];
    if (j < E) {
        int2 d[SPU]; ushort h[SPU];
#pragma unroll
        for (int u = 0; u < SPU; ++u) d[u] = eg[j + u];
#pragma unroll
        for (int u = 0; u < SPU; ++u) h[u] = Hb[(uint)d[u].x * 64u + lane];
        j += SPU;
        for (; j < E; j += SPU) {
            int2 dn[SPU]; ushort hn[SPU];
#pragma unroll
            for (int u = 0; u < SPU; ++u) dn[u] = eg[j + u];
#pragma unroll
            for (int u = 0; u < SPU; ++u) hn[u] = Hb[(uint)dn[u].x * 64u + lane];
#pragma unroll
            for (int u = 0; u < SPU; ++u)
                a += __int_as_float(d[u].y) * bf2f((uint)h[u]);
#pragma unroll
            for (int u = 0; u < SPU; ++u) { d[u] = dn[u]; h[u] = hn[u]; }
        }
#pragma unroll
        for (int u = 0; u < SPU; ++u)
            a += __int_as_float(d[u].y) * bf2f((uint)h[u]);
    }
    Sh[(size_t)r * 64 + lane] = f2bf(a);
}

// ---------------- reductions -----------------------------------------------
__global__ __launch_bounds__(256) void sqw_reduce_kernel(const float* __restrict__ W0,
                                                         const float* __restrict__ W1,
                                                         float* __restrict__ acc) {
    __shared__ float sm[4];
    float s = 0.f;
    for (int i = blockIdx.x * 256 + threadIdx.x; i < 40960; i += gridDim.x * 256) {
        float d = i < 32768 ? W0[i] : W1[i - 32768];
        s += d * d;
    }
#pragma unroll
    for (int off = 32; off > 0; off >>= 1) s += __shfl_down(s, off);
    int lane = threadIdx.x & 63, w = threadIdx.x >> 6;
    if (lane == 0) sm[w] = s;
    __syncthreads();
    if (threadIdx.x == 0) atomicAdd(acc, sm[0] + sm[1] + sm[2] + sm[3]);
}

__global__ __launch_bounds__(256) void partial_reduce_kernel(const float* __restrict__ p,
                                                             int n, float* __restrict__ acc) {
    __shared__ float sm[4];
    float s = 0.f;
    for (int i = threadIdx.x; i < n; i += 256) s += p[i];
#pragma unroll
    for (int off = 32; off > 0; off >>= 1) s += __shfl_down(s, off);
    int lane = threadIdx.x & 63, w = threadIdx.x >> 6;
    if (lane == 0) sm[w] = s;
    __syncthreads();
    if (threadIdx.x == 0) atomicAdd(acc, sm[0] + sm[1] + sm[2] + sm[3]);
}

__global__ void finalize_kernel(const float* __restrict__ acc, float* __restrict__ out) {
    out[0] = sqrtf(acc[0]) + 1e-4f * acc[1];
}

extern "C" void kernel_launch(void* const* d_in, const int* in_sizes, int n_in,
                              void* d_out, int out_size, void* d_ws, size_t ws_size,
                              hipStream_t stream) {
    const float* X    = (const float*)d_in[0];
    const float* W0   = (const float*)d_in[1];
    const float* W1   = (const float*)d_in[2];
    const float* v00  = (const float*)d_in[3];
    const float* v01  = (const float*)d_in[4];
    const float* pv00 = (const float*)d_in[5];
    const float* pv01 = (const float*)d_in[6];
    const int* rows   = (const int*)d_in[7];
    const int* cols   = (const int*)d_in[8];
    const int* prows  = (const int*)d_in[9];
    const int* pcols  = (const int*)d_in[10];

    float* out  = (float*)d_out;
    float* Henc = out + 1;                                  // N x 64 (misaligned base)
    float* Xrec = out + 1 + (size_t)N_NODES * 64;           // N x 256 (misaligned base)

    // scratch in dead X_ region [6400001, 32000001):
    ushort* bufAh  = (ushort*)(out + 6400004);              // N x 128 bf16 (H1)
    ushort* Sh     = (ushort*)(out + 6400004);              // N x 64 bf16 (after bufAh dead)
    int*    ccol   = (int*)(out + 12800004);                // 4.8M int (padded CSR)
    int2*   eg     = (int2*)(out + 17600004);               // 4.8M int2
    ushort* HencB  = (ushort*)(out + 27200004);             // N x 64 bf16
    int*    deg    = (int*)(out + 28800004);                // 2N
    int*    cur    = deg + TOT;                             // 2N

    float* ws   = (float*)d_ws;
    ushort* bufBh = (ushort*)ws;                            // N x 128 bf16 (D)
    float* f1   = ws + (size_t)N_NODES * 128;
    float* f2   = f1 + N_NODES;
    float* pf1  = f2 + N_NODES;
    float* pf2  = pf1 + N_NODES;
    float* acc  = pf2 + N_NODES;                            // 4
    ushort* B1cm = (ushort*)(acc + 4);                      // 128 x 264
    ushort* B7cm = B1cm + 128 * 264;                        // 128 x 72
    ushort* B8cm = B7cm + 128 * 72;                         // 256 x 136
    int*   rp   = (int*)(B8cm + 256 * 136);                 // 2N+1
    int*   bsum = rp + TOT + 1;                             // SCAN_NB
    float* partial = (float*)(bsum + SCAN_NB);              // cdiv(n,128)

    const int n = N_NODES;
    const int EG = cdiv(N_EDGES, 256);
    const int EG2 = cdiv(2 * (long)N_EDGES, 256);

    // 0. weight prep (B1 + B7 + B8)
    prep_all_kernel<<<cdiv(73728, 256), 256, 0, stream>>>(W0, W1, B1cm, B7cm, B8cm);

    // 1. H1 = X @ W0 -> bufAh (bf16) + fused attention dots, MFMA
    gemm_mfma<256, 128, true, 2, false, false, true><<<cdiv(n, 128), 256, 0, stream>>>(
        X, B1cm, bufAh, nullptr, nullptr, nullptr,
        v00, v01, pv00, pv01, f1, f2, pf1, pf2, n);

    // zero deg+cur and acc
    hipMemsetAsync(deg, 0, 2 * (size_t)TOT * sizeof(int), stream);
    hipMemsetAsync(acc, 0, 4 * sizeof(float), stream);

    // 2. padded interleaved CSR (bucket = 2r+adj) + pre-scaled softmax weights
    hist2_kernel<<<EG2, 256, 0, stream>>>(rows, prows, deg);
    scan1_kernel<<<SCAN_NB, 256, 0, stream>>>(deg, bsum);
    scan3_kernel<<<SCAN_NB, 256, 0, stream>>>(deg, bsum, rp);
    scatter_kernel<<<EG, 256, 0, stream>>>(rows, cols, 0, rp, cur, ccol);
    scatter_kernel<<<EG, 256, 0, stream>>>(prows, pcols, 1, rp, cur, ccol);
    edgeval_kernel<<<cdiv(TOT, 16), 256, 0, stream>>>(rp, deg, ccol,
                                                      f1, f2, pf1, pf2, eg);

    // 3. encoder spmm + fused @W1: -> Henc (fp32, d_out) + HencB (bf16)
    spmm_enc_kernel<<<n / 4, 256, 0, stream>>>(rp, eg, bufAh, W1, Henc, HencB);

    // 4. decoder spmm on HencB (lean) -> Sh (bf16, bufAh region now dead)
    spmm64_fused_kernel<<<n / 4, 256, 0, stream>>>(rp, eg, HencB, Sh);

    // 5. D = elu(Sh @ W1T) -> bufBh (bf16), MFMA
    gemm_mfma<64, 128, false, 2, true, false, false><<<cdiv(n, 128), 256, 0, stream>>>(
        Sh, B7cm, bufBh, nullptr, nullptr, nullptr,
        nullptr, nullptr, nullptr, nullptr, nullptr, nullptr, nullptr, nullptr, n);

    // 6. X_ = bufBh @ W0T -> Xrec + fused loss partials, MFMA
    gemm_mfma<128, 256, false, 0, false, true, false><<<cdiv(n, 128), 256, 0, stream>>>(
        bufBh, B8cm, Xrec, nullptr, X, partial,
        nullptr, nullptr, nullptr, nullptr, nullptr, nullptr, nullptr, nullptr, n);

    // 7. loss
    partial_reduce_kernel<<<1, 256, 0, stream>>>(partial, cdiv(n, 128), acc + 0);
    sqw_reduce_kernel<<<20, 256, 0, stream>>>(W0, W1, acc + 1);
    finalize_kernel<<<1, 1, 0, stream>>>(acc, out);
}

// Round 21
// 747.876 us; speedup vs baseline: 1.4186x; 1.0193x over previous
//
#include <hip/hip_runtime.h>
#include <math.h>

#define N_NODES 100000
#define N_EDGES 1600000
#define TOT (2 * N_NODES)            // CSR buckets: 2*row + adj
#define SCAN_NB 256
#define SCAN_CH 4                    // 256*256*4 = 262144 >= 2N+1

static inline int cdiv(long a, long b) { return (int)((a + b - 1) / b); }

typedef unsigned int uint;
typedef unsigned short ushort;
typedef __attribute__((ext_vector_type(8))) short short8v;   // 8 bf16 (4 VGPR)
typedef __attribute__((ext_vector_type(4))) float f32x4;

__device__ inline float bf2f(uint u) { return __uint_as_float(u << 16); }
__device__ inline ushort f2bf(float f) {
    uint u = __float_as_uint(f);
    uint r = ((u >> 16) & 1u) + 0x7fffu;   // RNE
    return (ushort)((u + r) >> 16);
}

// ---------------- MFMA bf16 GEMM: C[i,m] = sum_k A[i,k]*B[k,m] --------------
// ATTN (M==128 only): fused attention feature dots from fp32 accumulators.
template <int K, int M, bool AF32, int OUT, bool ELU, bool LOSS, bool ATTN>
__global__ __launch_bounds__(256) void gemm_mfma(const void* __restrict__ Av,
                                                 const ushort* __restrict__ Bcm,
                                                 void* __restrict__ Cv,
                                                 void* __restrict__ Cv2,
                                                 const float* __restrict__ Xref,
                                                 float* __restrict__ partial,
                                                 const float* __restrict__ va,
                                                 const float* __restrict__ vb,
                                                 const float* __restrict__ pva,
                                                 const float* __restrict__ pvb,
                                                 float* __restrict__ f1,
                                                 float* __restrict__ f2,
                                                 float* __restrict__ pf1,
                                                 float* __restrict__ pf2,
                                                 int nrows) {
    constexpr int BM = 128;
    constexpr int KP = K + 8;
    constexpr int NCT = M / 16;
    __shared__ ushort Blds[M * KP];
    __shared__ ushort Alds[BM * 32];
    const int w = threadIdx.x >> 6;
    const int l = threadIdx.x & 63;
    const int rowg = l & 15;
    const int kg = l >> 4;
    const int rbase = blockIdx.x * BM;
    {
        const uint4* src = reinterpret_cast<const uint4*>(Bcm);
        uint4* dst = reinterpret_cast<uint4*>(Blds);
        const int total = M * KP / 8;
        for (int i = threadIdx.x; i < total; i += 256) dst[i] = src[i];
    }
    f32x4 acc[2][NCT] = {};
    for (int k0 = 0; k0 < K; k0 += 32) {
        __syncthreads();
        int r = threadIdx.x >> 1;
        int kk = (threadIdx.x & 1) * 16;
        int rg = min(rbase + r, nrows - 1);
        if (AF32) {
            const float* A = (const float*)Av;
            const float4* src = reinterpret_cast<const float4*>(A + (size_t)rg * K + k0 + kk);
            ushort* dst = &Alds[r * 32 + kk];
#pragma unroll
            for (int q = 0; q < 4; ++q) {
                float4 v = src[q];
                dst[4 * q + 0] = f2bf(v.x); dst[4 * q + 1] = f2bf(v.y);
                dst[4 * q + 2] = f2bf(v.z); dst[4 * q + 3] = f2bf(v.w);
            }
        } else {
            const ushort* A = (const ushort*)Av;
            const uint4* src = reinterpret_cast<const uint4*>(A + (size_t)rg * K + k0 + kk);
            uint4* dst = reinterpret_cast<uint4*>(&Alds[r * 32 + kk]);
            dst[0] = src[0];
            dst[1] = src[1];
        }
        __syncthreads();
#pragma unroll
        for (int rt = 0; rt < 2; ++rt) {
            short8v af = *reinterpret_cast<const short8v*>(
                &Alds[(w * 32 + rt * 16 + rowg) * 32 + kg * 8]);
#pragma unroll
            for (int ct = 0; ct < NCT; ++ct) {
                short8v bf = *reinterpret_cast<const short8v*>(
                    &Blds[(ct * 16 + rowg) * KP + k0 + kg * 8]);
                acc[rt][ct] = __builtin_amdgcn_mfma_f32_16x16x32_bf16(
                    af, bf, acc[rt][ct], 0, 0, 0);
            }
        }
    }
    float lsum = 0.f;
#pragma unroll
    for (int rt = 0; rt < 2; ++rt) {
#pragma unroll
        for (int q = 0; q < 4; ++q) {
            int r = rbase + w * 32 + rt * 16 + kg * 4 + q;
            if (r >= nrows) continue;
#pragma unroll
            for (int ct = 0; ct < NCT; ++ct) {
                float o = acc[rt][ct][q];
                if (ELU) o = o > 0.f ? o : expm1f(o);
                int col = ct * 16 + rowg;
                if (OUT == 0 || OUT == 3) ((float*)Cv)[(size_t)r * M + col] = o;
                if (OUT == 2) ((ushort*)Cv)[(size_t)r * M + col] = f2bf(o);
                if (OUT == 3) ((ushort*)Cv2)[(size_t)r * M + col] = f2bf(o);
                if (LOSS) {
                    float d = o - Xref[(size_t)r * 256 + col];
                    lsum += d * d;
                }
            }
        }
    }
    if (ATTN) {
        float var[NCT], vbr[NCT], pvar[NCT], pvbr[NCT];
#pragma unroll
        for (int ct = 0; ct < NCT; ++ct) {
            int col = ct * 16 + rowg;
            var[ct] = va[col]; vbr[ct] = vb[col];
            pvar[ct] = pva[col]; pvbr[ct] = pvb[col];
        }
#pragma unroll
        for (int rt = 0; rt < 2; ++rt) {
#pragma unroll
            for (int q = 0; q < 4; ++q) {
                int r = rbase + w * 32 + rt * 16 + kg * 4 + q;
                float da = 0.f, db = 0.f, dpa = 0.f, dpb = 0.f;
#pragma unroll
                for (int ct = 0; ct < NCT; ++ct) {
                    float o = acc[rt][ct][q];
                    da += o * var[ct]; db += o * vbr[ct];
                    dpa += o * pvar[ct]; dpb += o * pvbr[ct];
                }
#pragma unroll
                for (int m = 1; m < 16; m <<= 1) {
                    da += __shfl_xor(da, m); db += __shfl_xor(db, m);
                    dpa += __shfl_xor(dpa, m); dpb += __shfl_xor(dpb, m);
                }
                if (rowg == 0 && r < nrows) {
                    f1[r] = da; f2[r] = db; pf1[r] = dpa; pf2[r] = dpb;
                }
            }
        }
    }
    if (LOSS) {
        __shared__ float smRed[4];
#pragma unroll
        for (int off = 32; off > 0; off >>= 1) lsum += __shfl_down(lsum, off);
        __syncthreads();
        if (l == 0) smRed[w] = lsum;
        __syncthreads();
        if (threadIdx.x == 0)
            partial[blockIdx.x] = smRed[0] + smRed[1] + smRed[2] + smRed[3];
    }
}

// ---------------- weight prep: B1 + B5 + B7 + B8 ----------------------------
__global__ __launch_bounds__(256) void prep_all_kernel(const float* __restrict__ W0,
                                                       const float* __restrict__ W1,
                                                       ushort* __restrict__ B1,
                                                       ushort* __restrict__ B5,
                                                       ushort* __restrict__ B7,
                                                       ushort* __restrict__ B8) {
    int i = blockIdx.x * 256 + threadIdx.x;
    if (i < 32768) {                            // B1[m][k] = W0[k][m], K=256 M=128
        int k = i / 128, m = i - k * 128;
        B1[m * 264 + k] = f2bf(W0[i]);
    } else if (i < 65536) {                     // B8[m][k] = W0[m][k], K=128 M=256
        int j = i - 32768;
        int m = j / 128, k = j - m * 128;
        B8[m * 136 + k] = f2bf(W0[j]);
    } else if (i < 73728) {                     // B5[m][k] = W1[k][m], K=128 M=64
        int j = i - 65536;
        int k = j / 64, m = j - k * 64;
        B5[m * 136 + k] = f2bf(W1[j]);
    } else if (i < 81920) {                     // B7[m][k] = W1[m][k], K=64 M=128
        int j = i - 73728;
        int m = j / 64, k = j - m * 64;
        B7[m * 72 + k] = f2bf(W1[j]);
    }
}

// ---------------- CSR build: bucket = 2*row + adj, rows padded to x8 --------
__global__ __launch_bounds__(256) void hist2_kernel(const int* __restrict__ rows,
                                                    const int* __restrict__ prows,
                                                    int* __restrict__ deg) {
    int e = blockIdx.x * 256 + threadIdx.x;
    if (e >= 2 * N_EDGES) return;
    int b = e < N_EDGES ? rows[e] * 2 : prows[e - N_EDGES] * 2 + 1;
    atomicAdd(&deg[b], 1);
}

__device__ inline int pad8(int d) { return (d + 7) & ~7; }

__global__ __launch_bounds__(256) void scan1_kernel(const int* __restrict__ deg,
                                                    int* __restrict__ bsum) {
    __shared__ int sm[256];
    int base = (blockIdx.x * 256 + threadIdx.x) * SCAN_CH;
    int s = 0;
#pragma unroll
    for (int i = 0; i < SCAN_CH; ++i) {
        int idx = base + i;
        if (idx < TOT) s += pad8(deg[idx]);
    }
    sm[threadIdx.x] = s;
    __syncthreads();
    for (int off = 128; off > 0; off >>= 1) {
        if (threadIdx.x < off) sm[threadIdx.x] += sm[threadIdx.x + off];
        __syncthreads();
    }
    if (threadIdx.x == 0) bsum[blockIdx.x] = sm[0];
}

__global__ __launch_bounds__(256) void scan3_kernel(const int* __restrict__ deg,
                                                    const int* __restrict__ bsum,
                                                    int* __restrict__ rp) {
    __shared__ int sm[256];
    __shared__ int base0;
    if (threadIdx.x == 0) {
        int run = 0;
        for (int i = 0; i < blockIdx.x; ++i) run += bsum[i];
        base0 = run;
    }
    int base = (blockIdx.x * 256 + threadIdx.x) * SCAN_CH;
    int s = 0;
#pragma unroll
    for (int i = 0; i < SCAN_CH; ++i) {
        int idx = base + i;
        if (idx < TOT) s += pad8(deg[idx]);
    }
    sm[threadIdx.x] = s;
    __syncthreads();
    if (threadIdx.x == 0) {
        int run = base0;
        for (int t = 0; t < 256; ++t) { int tmp = sm[t]; sm[t] = run; run += tmp; }
    }
    __syncthreads();
    int off = sm[threadIdx.x];
#pragma unroll
    for (int i = 0; i < SCAN_CH; ++i) {
        int idx = base + i;
        if (idx < TOT) { rp[idx] = off; off += pad8(deg[idx]); }
        else if (idx == TOT) rp[idx] = off;
    }
}

__global__ __launch_bounds__(256) void scatter_kernel(const int* __restrict__ rlist,
                                                      const int* __restrict__ clist,
                                                      int adj,
                                                      const int* __restrict__ rp,
                                                      int* __restrict__ cur,
                                                      int* __restrict__ ccol) {
    int e = blockIdx.x * 256 + threadIdx.x;
    if (e >= N_EDGES) return;
    int b = rlist[e] * 2 + adj;
    int pos = rp[b] + atomicAdd(&cur[b], 1);
    ccol[pos] = clist[e];
}

// -------- edge weights: bf16 stream; pads get wgt=0 AND ccol=0 --------------
__global__ __launch_bounds__(256) void edgeval_kernel(const int* __restrict__ rp,
                                                      const int* __restrict__ deg,
                                                      int* __restrict__ ccol,
                                                      const float* __restrict__ f1,
                                                      const float* __restrict__ f2,
                                                      const float* __restrict__ pf1,
                                                      const float* __restrict__ pf2,
                                                      ushort* __restrict__ wgt) {
    int b = blockIdx.x * 16 + (threadIdx.x >> 4);
    int sl = threadIdx.x & 15;
    int adj = b & 1, r = b >> 1;
    float f1r = adj ? pf1[r] : f1[r];
    const float* f2t = adj ? pf2 : f2;
    float scale = adj ? 0.8f : 0.2f;
    int j0 = rp[b];
    int realend = j0 + deg[b];
    int pend = rp[b + 1];
    float s = 0.f;
    for (int j = j0 + sl; j < realend; j += 16)
        s += __expf(f1r + f2t[ccol[j]]);
#pragma unroll
    for (int off = 8; off > 0; off >>= 1) s += __shfl_xor(s, off);
    float inv = s > 0.f ? scale / s : 0.f;
    for (int j = j0 + sl; j < pend; j += 16) {
        if (j < realend) {
            float wv = __expf(f1r + f2t[ccol[j]]) * inv;
            wgt[j] = f2bf(wv);
        } else {
            wgt[j] = 0;
            ccol[j] = 0;
        }
    }
}

// ---------------- encoder spmm (split streams): emits packed bf16 -----------
#define SPU 8
__global__ __launch_bounds__(256) void spmm_fused_kernel(const int* __restrict__ rp,
                                                         const int* __restrict__ ccol,
                                                         const ushort* __restrict__ wgt,
                                                         const ushort* __restrict__ Hb,
                                                         uint* __restrict__ outh) {
    int r = blockIdx.x * 4 + (threadIdx.x >> 6);
    int lane = threadIdx.x & 63;
    const uint* Hu = reinterpret_cast<const uint*>(Hb);
    float a0 = 0.f, a1 = 0.f;
    int j = rp[2 * r], E = rp[2 * r + 2];
    if (j < E) {
        int c[SPU]; float v[SPU]; uint h[SPU];
#pragma unroll
        for (int u = 0; u < SPU; ++u) c[u] = ccol[j + u];
#pragma unroll
        for (int u = 0; u < SPU; ++u) v[u] = bf2f((uint)wgt[j + u]);
#pragma unroll
        for (int u = 0; u < SPU; ++u) h[u] = Hu[(uint)c[u] * 64u + lane];
        j += SPU;
        for (; j < E; j += SPU) {
            int cn[SPU]; float vn[SPU]; uint hn[SPU];
#pragma unroll
            for (int u = 0; u < SPU; ++u) cn[u] = ccol[j + u];
#pragma unroll
            for (int u = 0; u < SPU; ++u) vn[u] = bf2f((uint)wgt[j + u]);
#pragma unroll
            for (int u = 0; u < SPU; ++u) hn[u] = Hu[(uint)cn[u] * 64u + lane];
#pragma unroll
            for (int u = 0; u < SPU; ++u) {
                a0 += v[u] * bf2f(h[u] & 0xffffu);
                a1 += v[u] * bf2f(h[u] >> 16);
            }
#pragma unroll
            for (int u = 0; u < SPU; ++u) { v[u] = vn[u]; h[u] = hn[u]; }
        }
#pragma unroll
        for (int u = 0; u < SPU; ++u) {
            a0 += v[u] * bf2f(h[u] & 0xffffu);
            a1 += v[u] * bf2f(h[u] >> 16);
        }
    }
    float o0 = a0 > 0.f ? a0 : expm1f(a0);
    float o1 = a1 > 0.f ? a1 : expm1f(a1);
    outh[(size_t)r * 64 + lane] = (uint)f2bf(o0) | ((uint)f2bf(o1) << 16);
}

// ---------------- decoder spmm (split streams): emits bf16 S ----------------
__global__ __launch_bounds__(256) void spmm64_fused_kernel(const int* __restrict__ rp,
                                                           const int* __restrict__ ccol,
                                                           const ushort* __restrict__ wgt,
                                                           const ushort* __restrict__ Hb,
                                                           ushort* __restrict__ Sh) {
    int r = blockIdx.x * 4 + (threadIdx.x >> 6);
    int lane = threadIdx.x & 63;
    float a = 0.f;
    int j = rp[2 * r], E = rp[2 * r + 2];
    if (j < E) {
        int c[SPU]; float v[SPU]; ushort h[SPU];
#pragma unroll
        for (int u = 0; u < SPU; ++u) c[u] = ccol[j + u];
#pragma unroll
        for (int u = 0; u < SPU; ++u) v[u] = bf2f((uint)wgt[j + u]);
#pragma unroll
        for (int u = 0; u < SPU; ++u) h[u] = Hb[(uint)c[u] * 64u + lane];
        j += SPU;
        for (; j < E; j += SPU) {
            int cn[SPU]; float vn[SPU]; ushort hn[SPU];
#pragma unroll
            for (int u = 0; u < SPU; ++u) cn[u] = ccol[j + u];
#pragma unroll
            for (int u = 0; u < SPU; ++u) vn[u] = bf2f((uint)wgt[j + u]);
#pragma unroll
            for (int u = 0; u < SPU; ++u) hn[u] = Hb[(uint)cn[u] * 64u + lane];
#pragma unroll
            for (int u = 0; u < SPU; ++u)
                a += v[u] * bf2f((uint)h[u]);
#pragma unroll
            for (int u = 0; u < SPU; ++u) { v[u] = vn[u]; h[u] = hn[u]; }
        }
#pragma unroll
        for (int u = 0; u < SPU; ++u)
            a += v[u] * bf2f((uint)h[u]);
    }
    Sh[(size_t)r * 64 + lane] = f2bf(a);
}

// ---------------- reductions -----------------------------------------------
__global__ __launch_bounds__(256) void sqw_reduce_kernel(const float* __restrict__ W0,
                                                         const float* __restrict__ W1,
                                                         float* __restrict__ acc) {
    __shared__ float sm[4];
    float s = 0.f;
    for (int i = blockIdx.x * 256 + threadIdx.x; i < 40960; i += gridDim.x * 256) {
        float d = i < 32768 ? W0[i] : W1[i - 32768];
        s += d * d;
    }
#pragma unroll
    for (int off = 32; off > 0; off >>= 1) s += __shfl_down(s, off);
    int lane = threadIdx.x & 63, w = threadIdx.x >> 6;
    if (lane == 0) sm[w] = s;
    __syncthreads();
    if (threadIdx.x == 0) atomicAdd(acc, sm[0] + sm[1] + sm[2] + sm[3]);
}

__global__ __launch_bounds__(256) void partial_reduce_kernel(const float* __restrict__ p,
                                                             int n, float* __restrict__ acc) {
    __shared__ float sm[4];
    float s = 0.f;
    for (int i = threadIdx.x; i < n; i += 256) s += p[i];
#pragma unroll
    for (int off = 32; off > 0; off >>= 1) s += __shfl_down(s, off);
    int lane = threadIdx.x & 63, w = threadIdx.x >> 6;
    if (lane == 0) sm[w] = s;
    __syncthreads();
    if (threadIdx.x == 0) atomicAdd(acc, sm[0] + sm[1] + sm[2] + sm[3]);
}

__global__ void finalize_kernel(const float* __restrict__ acc, float* __restrict__ out) {
    out[0] = sqrtf(acc[0]) + 1e-4f * acc[1];
}

extern "C" void kernel_launch(void* const* d_in, const int* in_sizes, int n_in,
                              void* d_out, int out_size, void* d_ws, size_t ws_size,
                              hipStream_t stream) {
    const float* X    = (const float*)d_in[0];
    const float* W0   = (const float*)d_in[1];
    const float* W1   = (const float*)d_in[2];
    const float* v00  = (const float*)d_in[3];
    const float* v01  = (const float*)d_in[4];
    const float* pv00 = (const float*)d_in[5];
    const float* pv01 = (const float*)d_in[6];
    const int* rows   = (const int*)d_in[7];
    const int* cols   = (const int*)d_in[8];
    const int* prows  = (const int*)d_in[9];
    const int* pcols  = (const int*)d_in[10];

    float* out  = (float*)d_out;
    float* Henc = out + 1;                                  // N x 64 (misaligned base)
    float* Xrec = out + 1 + (size_t)N_NODES * 64;           // N x 256 (misaligned base)

    // scratch in dead X_ region [6400001, 32000001):
    ushort* bufAh  = (ushort*)(out + 6400004);              // N x 128 bf16 (H1)
    ushort* Sh     = (ushort*)(out + 6400004);              // N x 64 bf16 (after bufAh dead)
    int*    ccol   = (int*)(out + 12800004);                // 4.8M int (padded CSR)
    ushort* wgt    = (ushort*)(out + 17600004);             // 4.8M ushort (bf16 weights)
    ushort* HencB  = (ushort*)(out + 27200004);             // N x 64 bf16
    int*    deg    = (int*)(out + 28800004);                // 2N
    int*    cur    = deg + TOT;                             // 2N

    float* ws   = (float*)d_ws;
    ushort* bufBh = (ushort*)ws;                            // N x 128 bf16 (enc out / D)
    float* f1   = ws + (size_t)N_NODES * 128;
    float* f2   = f1 + N_NODES;
    float* pf1  = f2 + N_NODES;
    float* pf2  = pf1 + N_NODES;
    float* acc  = pf2 + N_NODES;                            // 4
    ushort* B1cm = (ushort*)(acc + 4);                      // 128 x 264
    ushort* B5cm = B1cm + 128 * 264;                        // 64 x 136
    ushort* B7cm = B5cm + 64 * 136;                         // 128 x 72
    ushort* B8cm = B7cm + 128 * 72;                         // 256 x 136
    int*   rp   = (int*)(B8cm + 256 * 136);                 // 2N+1
    int*   bsum = rp + TOT + 1;                             // SCAN_NB
    float* partial = (float*)(bsum + SCAN_NB);              // cdiv(n,128)

    const int n = N_NODES;
    const int EG = cdiv(N_EDGES, 256);
    const int EG2 = cdiv(2 * (long)N_EDGES, 256);

    // 0. weight prep
    prep_all_kernel<<<cdiv(81920, 256), 256, 0, stream>>>(W0, W1, B1cm, B5cm, B7cm, B8cm);

    // 1. H1 = X @ W0 -> bufAh (bf16) + fused attention dots, MFMA
    gemm_mfma<256, 128, true, 2, false, false, true><<<cdiv(n, 128), 256, 0, stream>>>(
        X, B1cm, bufAh, nullptr, nullptr, nullptr,
        v00, v01, pv00, pv01, f1, f2, pf1, pf2, n);

    // zero deg+cur and acc
    hipMemsetAsync(deg, 0, 2 * (size_t)TOT * sizeof(int), stream);
    hipMemsetAsync(acc, 0, 4 * sizeof(float), stream);

    // 2. padded interleaved CSR (bucket = 2r+adj) + bf16 softmax weight stream
    hist2_kernel<<<EG2, 256, 0, stream>>>(rows, prows, deg);
    scan1_kernel<<<SCAN_NB, 256, 0, stream>>>(deg, bsum);
    scan3_kernel<<<SCAN_NB, 256, 0, stream>>>(deg, bsum, rp);
    scatter_kernel<<<EG, 256, 0, stream>>>(rows, cols, 0, rp, cur, ccol);
    scatter_kernel<<<EG, 256, 0, stream>>>(prows, pcols, 1, rp, cur, ccol);
    edgeval_kernel<<<cdiv(TOT, 16), 256, 0, stream>>>(rp, deg, ccol,
                                                      f1, f2, pf1, pf2, wgt);

    // 3. encoder spmm -> bufBh (bf16)
    spmm_fused_kernel<<<n / 4, 256, 0, stream>>>(rp, ccol, wgt, bufAh, (uint*)bufBh);

    // 4. Henc = bufBh @ W1 -> Henc (fp32, d_out) + HencB (bf16), MFMA
    gemm_mfma<128, 64, false, 3, false, false, false><<<cdiv(n, 128), 256, 0, stream>>>(
        bufBh, B5cm, Henc, HencB, nullptr, nullptr,
        nullptr, nullptr, nullptr, nullptr, nullptr, nullptr, nullptr, nullptr, n);

    // 5. decoder spmm on HencB -> Sh (bf16, bufAh region now dead)
    spmm64_fused_kernel<<<n / 4, 256, 0, stream>>>(rp, ccol, wgt, HencB, Sh);

    // 6. D = elu(Sh @ W1T) -> bufBh (bf16), MFMA
    gemm_mfma<64, 128, false, 2, true, false, false><<<cdiv(n, 128), 256, 0, stream>>>(
        Sh, B7cm, bufBh, nullptr, nullptr, nullptr,
        nullptr, nullptr, nullptr, nullptr, nullptr, nullptr, nullptr, nullptr, n);

    // 7. X_ = bufBh @ W0T -> Xrec + fused loss partials, MFMA
    gemm_mfma<128, 256, false, 0, false, true, false><<<cdiv(n, 128), 256, 0, stream>>>(
        bufBh, B8cm, Xrec, nullptr, X, partial,
        nullptr, nullptr, nullptr, nullptr, nullptr, nullptr, nullptr, nullptr, n);

    // 8. loss
    partial_reduce_kernel<<<1, 256, 0, stream>>>(partial, cdiv(n, 128), acc + 0);
    sqw_reduce_kernel<<<20, 256, 0, stream>>>(W0, W1, acc + 1);
    finalize_kernel<<<1, 1, 0, stream>>>(acc, out);
}